// Round 5
// baseline (2485.578 us; speedup 1.0000x reference)
//
#include <hip/hip_runtime.h>
#include <math.h>

#define B_ 64
#define T_ 32
#define D_ 128
#define N_ 128
#define ST 136      // ushort stride of slab rows (128 cols + 8 pad), 272 B

typedef __attribute__((ext_vector_type(8))) short s8v;
typedef __attribute__((ext_vector_type(4))) float f4;
typedef __attribute__((ext_vector_type(4))) unsigned short us4;

__device__ __forceinline__ float softplus_f(float v){ return (v > 20.f) ? v : log1pf(expf(v)); }
__device__ __forceinline__ float sigmoid_f(float v){ return 1.f / (1.f + expf(-v)); }
__device__ __forceinline__ float bf2f(unsigned short u){ return __uint_as_float(((unsigned)u) << 16); }
__device__ __forceinline__ float wred(float v){
#pragma unroll
    for (int o = 32; o > 0; o >>= 1) v += __shfl_down(v, o, 64);
    return v;
}
// fp32 -> bf16 hi (RN) + bf16 lo (RN of remainder): covers ~16 mantissa bits.
__device__ __forceinline__ void split2(float v, unsigned short& h, unsigned short& l){
    unsigned int u  = __float_as_uint(v);
    unsigned int rh = u + 0x7fffu + ((u >> 16) & 1u);
    h = (unsigned short)(rh >> 16);
    float fh = __uint_as_float(rh & 0xffff0000u);
    float lo = v - fh;
    unsigned int ul = __float_as_uint(lo);
    unsigned int rl = ul + 0x7fffu + ((ul >> 16) & 1u);
    l = (unsigned short)(rl >> 16);
}
__device__ __forceinline__ void split4_store(float4 v, unsigned short* hp, unsigned short* lp){
    unsigned short h0,h1,h2,h3,l0,l1,l2,l3;
    split2(v.x,h0,l0); split2(v.y,h1,l1); split2(v.z,h2,l2); split2(v.w,h3,l3);
    uint2 H = make_uint2((unsigned)h0 | ((unsigned)h1 << 16), (unsigned)h2 | ((unsigned)h3 << 16));
    uint2 L = make_uint2((unsigned)l0 | ((unsigned)l1 << 16), (unsigned)l2 | ((unsigned)l3 << 16));
    *(uint2*)hp = H; *(uint2*)lp = L;
}
__device__ __forceinline__ f4 mfma3(s8v ah, s8v al, s8v bh, s8v bl, f4 c){
    c = __builtin_amdgcn_mfma_f32_16x16x32_bf16(ah, bh, c, 0, 0, 0);
    c = __builtin_amdgcn_mfma_f32_16x16x32_bf16(ah, bl, c, 0, 0, 0);
    c = __builtin_amdgcn_mfma_f32_16x16x32_bf16(al, bh, c, 0, 0, 0);
    return c;
}

// mm1-type: A (S-split) from LDS, B from global WT planes. Rolling 2-deep B prefetch.
__device__ __forceinline__ void mm_bglob(const unsigned short* __restrict__ BH,
                                         const unsigned short* __restrict__ BL,
                                         const unsigned short* aHi,
                                         const unsigned short* aLo,
                                         int wi, int wn, int q, int lm, f4* acc)
{
    s8v bH[2][4], bL[2][4];
#pragma unroll
    for (int c = 0; c < 2; ++c){
        int k0 = c * 32 + q * 8;
#pragma unroll
        for (int nt = 0; nt < 4; ++nt){
            size_t off = (size_t)(wn * 64 + nt * 16 + lm) * 128 + k0;
            bH[c][nt] = *(const s8v*)&BH[off];
            bL[c][nt] = *(const s8v*)&BL[off];
        }
    }
#pragma unroll
    for (int c = 0; c < 4; ++c){
        int k0 = c * 32 + q * 8;
        s8v aH[2], aL[2];
#pragma unroll
        for (int s = 0; s < 2; ++s){
            int row = (wi * 2 + s) * 16 + lm;
            aH[s] = *(const s8v*)&aHi[row * ST + k0];
            aL[s] = *(const s8v*)&aLo[row * ST + k0];
        }
#pragma unroll
        for (int nt = 0; nt < 4; ++nt)
#pragma unroll
            for (int s = 0; s < 2; ++s)
                acc[s * 4 + nt] = mfma3(aH[s], aL[s], bH[c & 1][nt], bL[c & 1][nt], acc[s * 4 + nt]);
        if (c < 2){
            int k2 = (c + 2) * 32 + q * 8;
#pragma unroll
            for (int nt = 0; nt < 4; ++nt){
                size_t off = (size_t)(wn * 64 + nt * 16 + lm) * 128 + k2;
                bH[c][nt] = *(const s8v*)&BH[off];
                bL[c][nt] = *(const s8v*)&BL[off];
            }
        }
    }
}

// mm2-type: A from global WT planes, B (PT) from LDS. Rolling 2-deep A prefetch.
__device__ __forceinline__ void mm_aglob(const unsigned short* __restrict__ AH,
                                         const unsigned short* __restrict__ AL,
                                         const unsigned short* bHi,
                                         const unsigned short* bLo,
                                         int wi, int wn, int q, int lm, f4* acc)
{
    s8v aH[2][2], aL[2][2];
#pragma unroll
    for (int c = 0; c < 2; ++c){
        int k0 = c * 32 + q * 8;
#pragma unroll
        for (int s = 0; s < 2; ++s){
            size_t row = (size_t)((wi * 2 + s) * 16 + lm) * 128 + k0;
            aH[c][s] = *(const s8v*)&AH[row];
            aL[c][s] = *(const s8v*)&AL[row];
        }
    }
#pragma unroll
    for (int c = 0; c < 4; ++c){
        int k0 = c * 32 + q * 8;
#pragma unroll
        for (int nt = 0; nt < 4; ++nt){
            int j = wn * 64 + nt * 16 + lm;
            s8v bH = *(const s8v*)&bHi[j * ST + k0];
            s8v bL = *(const s8v*)&bLo[j * ST + k0];
#pragma unroll
            for (int s = 0; s < 2; ++s)
                acc[s * 4 + nt] = mfma3(aH[c & 1][s], aL[c & 1][s], bH, bL, acc[s * 4 + nt]);
        }
        if (c < 2){
            int k2 = (c + 2) * 32 + q * 8;
#pragma unroll
            for (int s = 0; s < 2; ++s){
                size_t row = (size_t)((wi * 2 + s) * 16 + lm) * 128 + k2;
                aH[c][s] = *(const s8v*)&AH[row];
                aL[c][s] = *(const s8v*)&AL[row];
            }
        }
    }
}

__device__ __forceinline__ void pt_stage(const f4* acc, unsigned short* hi, unsigned short* lo,
                                         int wi, int wn, int q, int lm)
{
#pragma unroll
    for (int s = 0; s < 2; ++s)
#pragma unroll
    for (int nt = 0; nt < 4; ++nt){
        f4 a = acc[s * 4 + nt];
        int kb = wi * 32 + s * 16 + q * 4;
        int jr = wn * 64 + nt * 16 + lm;
        split4_store(make_float4(a[0], a[1], a[2], a[3]),
                     &hi[jr * ST + kb], &lo[jr * ST + kb]);
    }
}

// ---- prep: split+transpose W into WT[n][l] bf16 hi/lo (n-major, l contiguous) ----
__global__ __launch_bounds__(256)
void prep_w(const float* __restrict__ Wz, const float* __restrict__ Wr,
            const float* __restrict__ Wh, unsigned short* __restrict__ WT){
    int gate = blockIdx.x, n0 = blockIdx.y * 16, tid = threadIdx.x;
    const float* W = (gate == 0) ? Wz : (gate == 1) ? Wr : Wh;
    unsigned short* hi = WT + (size_t)gate * 32768;
    unsigned short* lo = hi + 16384;
#pragma unroll
    for (int e = 0; e < 8; ++e){
        int idx = tid + e * 256;
        int n = n0 + (idx >> 7), k = idx & 127;
        float v = W[(size_t)k * 128 + n];
        unsigned short h, l; split2(v, h, l);
        hi[(size_t)n * 128 + k] = h;
        lo[(size_t)n * 128 + k] = l;
    }
}

// ---- prep: XU[g][bt][n] = x_bt . U_g  (g: 0=z,1=r,2=h), XX[bt] = ||x_bt||^2 ----
__global__ __launch_bounds__(256)
void prep_xu(const float* __restrict__ x, const float* __restrict__ Uz,
             const float* __restrict__ Ur, const float* __restrict__ Uh,
             float* __restrict__ XU, float* __restrict__ XX){
    int bt = blockIdx.x, tid = threadIdx.x;
    __shared__ float sX[128];
    __shared__ float sRed[256];
    __shared__ float sP[4];
    if (tid < 128) sX[tid] = x[(size_t)bt * 128 + tid];
    __syncthreads();
    {
        float v = (tid < 128) ? sX[tid] * sX[tid] : 0.f;
        v = wred(v);
        if ((tid & 63) == 0) sP[tid >> 6] = v;
    }
    const float* Us[3] = {Uz, Ur, Uh};
#pragma unroll 1
    for (int g = 0; g < 3; ++g){
        int n = tid & 127, hf = tid >> 7;
        float p = 0.f;
#pragma unroll 8
        for (int k = hf * 64; k < hf * 64 + 64; ++k) p = fmaf(sX[k], Us[g][(size_t)k * 128 + n], p);
        sRed[tid] = p;
        __syncthreads();
        if (tid < 128) XU[(size_t)g * (2048 * 128) + (size_t)bt * 128 + tid] = sRed[tid] + sRed[tid + 128];
        __syncthreads();
    }
    if (tid == 0) XX[bt] = sP[0] + sP[1] + sP[2] + sP[3];
}

// ---- fused recurrent kernel: one block per batch, full T loop in LDS ----
// 512 threads = 8 waves. S state lives ONLY as bf16 hi/lo split, ping-ponged
// between two slabs (read slab[cur], write slab[nxt] -> race-free, no fp32 copy).
// Gate matvec phases merged with mm1 MFMA phases; all mm phases use rolling
// 2-deep operand prefetch to batch the global WT load latency.
__global__ __launch_bounds__(512, 2)
void gru_fused(const float* __restrict__ Wz, const float* __restrict__ Wr,
               const float* __restrict__ Wh,
               const unsigned short* __restrict__ WT,
               const float* __restrict__ XU, const float* __restrict__ XX,
               const float* __restrict__ uzs, const float* __restrict__ wzs,
               const float* __restrict__ urs, const float* __restrict__ wrs,
               const float* __restrict__ uhs, const float* __restrict__ whs,
               float* __restrict__ mu_out, float* __restrict__ S_out)
{
    const int b = blockIdx.x, tid = threadIdx.x;
    const int w8 = tid >> 6, wi = w8 & 3, wn = w8 >> 2;
    const int q = (tid >> 4) & 3, lm = tid & 15;

    __shared__ alignas(16) unsigned short slab[2][2][128 * ST];   // [buf][hi/lo]
    __shared__ float sMuB[2][128];
    __shared__ float sZ[128], sGz[128], sR[128], sGr[128], sRh[128], sH[128], sGh[128];
    __shared__ float sSP[6][128];
    __shared__ float sRed[512];
    __shared__ float sScalTd[8], sScalP[2], sScalQ[2];
    __shared__ float sPt, sRR;

    const unsigned short* zH = WT;
    const unsigned short* zL = WT + 16384;
    const unsigned short* rH = WT + 32768;
    const unsigned short* rL = WT + 49152;
    const unsigned short* hH = WT + 65536;
    const unsigned short* hL = WT + 81920;

    for (int i = tid; i < 2 * 2 * 128 * ST; i += 512) ((unsigned short*)slab)[i] = 0;
    for (int a = tid; a < 768; a += 512){
        int tb = a >> 7, n = a & 127;
        const float* srcs[6] = {uzs, wzs, urs, wrs, uhs, whs};
        sSP[tb][n] = softplus_f(srcs[tb][n]);
    }
    if (tid < 128) sMuB[0][tid] = 0.f;
    __syncthreads();

    for (int t = 0; t < T_; ++t){
        const int bt = b * T_ + t;
        const int cur = t & 1, nxt = cur ^ 1;
        unsigned short* curHi = slab[cur][0];
        unsigned short* curLo = slab[cur][1];
        unsigned short* nxtHi = slab[nxt][0];
        unsigned short* nxtLo = slab[nxt][1];
        const float* muP = sMuB[t & 1];
        float* muN = sMuB[(t + 1) & 1];
        const float xxv = XX[bt];

        float xuzr = 0.f, xuh = 0.f;
        if (tid < 256) xuzr = XU[(size_t)(tid >> 7) * (2048 * 128) + (size_t)bt * 128 + (tid & 127)];
        if (tid < 128) xuh = XU[(size_t)2 * (2048 * 128) + (size_t)bt * 128 + tid];

        // ==== ph1: P1 z/r matvec partials (VALU+W loads) || mm1-z MFMA ====
        {
            int n = tid & 127, kq = (tid >> 7) & 1, g = tid >> 8;
            const float* Wg = g ? Wr : Wz;
            float p = 0.f;
#pragma unroll 8
            for (int k = kq * 64; k < kq * 64 + 64; ++k) p = fmaf(muP[k], Wg[(size_t)k * 128 + n], p);
            sRed[tid] = p;
        }
        f4 accZ[8];
#pragma unroll
        for (int i = 0; i < 8; ++i) accZ[i] = (f4){0.f, 0.f, 0.f, 0.f};
        mm_bglob(zH, zL, curHi, curLo, wi, wn, q, lm, accZ);
        __syncthreads();

        // ==== ph2: finalize z, r, rh | pp + trS reduce ====
        if (tid < 256){
            int g = tid >> 7, n = tid & 127;
            float a = xuzr + sRed[g * 256 + n] + sRed[g * 256 + 128 + n];
            float gg = sigmoid_f(a);
            if (!g){ sZ[n] = gg; sGz[n] = gg * (1.f - gg); }
            else   { sR[n] = gg; sGr[n] = gg * (1.f - gg); sRh[n] = muP[n] * gg; }
        } else if (tid < 384){
            int n = tid & 127;
            float d = bf2f(curHi[n * ST + n]) + bf2f(curLo[n * ST + n]);   // S_p[n][n]
            float v = muP[n] * muP[n] + d;
            v = wred(v);
            if ((tid & 63) == 0) sScalP[(tid >> 6) & 1] = v;
        }
        __syncthreads();

        // ==== ph3: P3 h matvec partials || mm1-r MFMA ====
        {
            int n = tid & 127, kq = tid >> 7;
            float p = 0.f;
#pragma unroll 8
            for (int k = kq * 32; k < kq * 32 + 32; ++k) p = fmaf(sRh[k], Wh[(size_t)k * 128 + n], p);
            sRed[tid] = p;
        }
        f4 accR[8];
#pragma unroll
        for (int i = 0; i < 8; ++i) accR[i] = (f4){0.f, 0.f, 0.f, 0.f};
        mm_bglob(rH, rL, curHi, curLo, wi, wn, q, lm, accR);
        __syncthreads();

        // ==== ph4: finalize h/mu | rr reduce | sPt ; PT_z stage into nxt ====
        if (tid < 128){
            float ah = xuh + sRed[tid] + sRed[tid + 128] + sRed[tid + 256] + sRed[tid + 384];
            float h = tanhf(ah);
            float z = sZ[tid];
            sH[tid] = h; sGh[tid] = 1.f - h * h;
            float m = z * muP[tid] + (1.f - z) * h;
            muN[tid] = m;
            __builtin_nontemporal_store(m, &mu_out[(size_t)bt * 128 + tid]);
        } else if (tid < 256){
            int n = tid & 127;
            float v = sRh[n] * sRh[n];
            v = wred(v);
            if ((tid & 63) == 0) sScalQ[(tid >> 6) & 1] = v;
        } else if (tid == 256){ sPt = sScalP[0] + sScalP[1]; }
        pt_stage(accZ, nxtHi, nxtLo, wi, wn, q, lm);
        __syncthreads();

        // ==== ph5: mm2-z + epilogue-z -> szc (regs) ====
        if (tid == 0) sRR = sScalQ[0] + sScalQ[1];
        float szc[32];
        {
            f4 acc[8];
#pragma unroll
            for (int i = 0; i < 8; ++i) acc[i] = (f4){0.f, 0.f, 0.f, 0.f};
            mm_aglob(zH, zL, nxtHi, nxtLo, wi, wn, q, lm, acc);
            float pt = sPt;
#pragma unroll
            for (int s = 0; s < 2; ++s)
#pragma unroll
            for (int nt = 0; nt < 4; ++nt){
                f4 a = acc[s * 4 + nt];
                int ib = wi * 32 + s * 16 + q * 4;
                int j  = wn * 64 + nt * 16 + lm;
                float gj = sGz[j];
#pragma unroll
                for (int r = 0; r < 4; ++r){
                    int i = ib + r;
                    float v = a[r];
                    if (i == j) v += pt * sSP[1][i] + xxv * sSP[0][i];
                    szc[s * 16 + nt * 4 + r] = v * sGz[i] * gj;
                }
            }
        }
        __syncthreads();

        // ==== ph6: PT_r stage into nxt ====
        pt_stage(accR, nxtHi, nxtLo, wi, wn, q, lm);
        __syncthreads();

        // ==== ph7: mm2-r MFMA ====
        f4 accR2[8];
#pragma unroll
        for (int i = 0; i < 8; ++i) accR2[i] = (f4){0.f, 0.f, 0.f, 0.f};
        mm_aglob(rH, rL, nxtHi, nxtLo, wi, wn, q, lm, accR2);
        __syncthreads();

        // ==== ph8: epilogue-r -> S_g staged (transposed; symmetric) into nxt ====
        {
            float pt = sPt;
            float td = 0.f;
#pragma unroll
            for (int s = 0; s < 2; ++s)
#pragma unroll
            for (int nt = 0; nt < 4; ++nt){
                f4 a = accR2[s * 4 + nt];
                int ib = wi * 32 + s * 16 + q * 4;
                int j  = wn * 64 + nt * 16 + lm;
                float gj = sGr[j], muj = muP[j], rj = sR[j];
                us4 h4 = *(const us4*)&curHi[j * ST + ib];
                us4 l4 = *(const us4*)&curLo[j * ST + ib];
                float sg[4];
#pragma unroll
                for (int r = 0; r < 4; ++r){
                    int i = ib + r;
                    float v = a[r];
                    if (i == j) v += pt * sSP[3][i] + xxv * sSP[2][i];
                    float srv = v * sGr[i] * gj;                 // S_r[i][j]
                    float spv = bf2f(h4[r]) + bf2f(l4[r]);       // S_p[i][j]
                    float gv = spv * srv + muP[i] * muj * srv + sR[i] * rj * spv;
                    if (i == j) td += gv;
                    sg[r] = gv;
                }
                split4_store(make_float4(sg[0], sg[1], sg[2], sg[3]),
                             &nxtHi[j * ST + ib], &nxtLo[j * ST + ib]);
            }
            td = wred(td);
            if ((tid & 63) == 0) sScalTd[w8] = td;
        }
        __syncthreads();

        // ==== ph9: mm1-h (A = S_g in nxt, B = WT_h) ====
        f4 accH[8];
#pragma unroll
        for (int i = 0; i < 8; ++i) accH[i] = (f4){0.f, 0.f, 0.f, 0.f};
        mm_bglob(hH, hL, nxtHi, nxtLo, wi, wn, q, lm, accH);
        __syncthreads();

        // ==== ph10: PT_h stage into nxt (S_g consumed) ====
        pt_stage(accH, nxtHi, nxtLo, wi, wn, q, lm);
        __syncthreads();

        // ==== ph11: mm2-h ====
        f4 accC[8];
#pragma unroll
        for (int i = 0; i < 8; ++i) accC[i] = (f4){0.f, 0.f, 0.f, 0.f};
        mm_aglob(hH, hL, nxtHi, nxtLo, wi, wn, q, lm, accC);
        __syncthreads();

        // ==== ph12: final combine; NT-write S_out; write next S-split into nxt ====
        {
            float trg = 0.f;
#pragma unroll
            for (int k = 0; k < 8; ++k) trg += sScalTd[k];
            float coef = sRR + trg;                 // rr + tr(S_g)
            float* outS = S_out + (size_t)bt * 16384;
#pragma unroll
            for (int s = 0; s < 2; ++s)
#pragma unroll
            for (int nt = 0; nt < 4; ++nt){
                f4 a = accC[s * 4 + nt];
                int ib = wi * 32 + s * 16 + q * 4;
                int j  = wn * 64 + nt * 16 + lm;
                float zj = sZ[j], ghj = sGh[j], dmj = muP[j] - sH[j];
                us4 h4 = *(const us4*)&curHi[j * ST + ib];
                us4 l4 = *(const us4*)&curLo[j * ST + ib];
                f4 sv4;
#pragma unroll
                for (int r = 0; r < 4; ++r){
                    int i = ib + r;
                    float shh = a[r];
                    if (i == j) shh += coef * sSP[5][i] + xxv * sSP[4][i];
                    float sh = shh * sGh[i] * ghj;
                    float szv = szc[s * 16 + nt * 4 + r];
                    float spv = bf2f(h4[r]) + bf2f(l4[r]);       // S_p[i][j]
                    float dmi = muP[i] - sH[i];
                    float zi = sZ[i];
                    float sv = szv * (spv + sh + dmi * dmj) + zi * zj * spv + (1.f - zi) * (1.f - zj) * sh;
                    if (!isfinite(sv)) sv = 0.f;
                    if (i == j) sv = fabsf(sv);
                    sv4[r] = sv;
                }
                __builtin_nontemporal_store(sv4, (f4*)&outS[(size_t)j * 128 + ib]);
                split4_store(make_float4(sv4[0], sv4[1], sv4[2], sv4[3]),
                             &nxtHi[j * ST + ib], &nxtLo[j * ST + ib]);
            }
        }
        __syncthreads();    // end of step: slab[nxt] is the new S-split; mu ready
    }
}

extern "C" void kernel_launch(void* const* d_in, const int* in_sizes, int n_in,
                              void* d_out, int out_size, void* d_ws, size_t ws_size,
                              hipStream_t stream)
{
    (void)in_sizes; (void)n_in; (void)out_size; (void)ws_size;
    const float* x   = (const float*)d_in[0];
    const float* Uz  = (const float*)d_in[1];
    const float* Wz  = (const float*)d_in[2];
    const float* Ur  = (const float*)d_in[3];
    const float* Wr  = (const float*)d_in[4];
    const float* Uh  = (const float*)d_in[5];
    const float* Wh  = (const float*)d_in[6];
    const float* uzs = (const float*)d_in[7];
    const float* wzs = (const float*)d_in[8];
    const float* urs = (const float*)d_in[9];
    const float* wrs = (const float*)d_in[10];
    const float* uhs = (const float*)d_in[11];
    const float* whs = (const float*)d_in[12];

    float* mu_out = (float*)d_out;
    float* S_out  = (float*)d_out + (size_t)B_ * T_ * N_;

    char* ws = (char*)d_ws;
    unsigned short* wsWT = (unsigned short*)ws;                 // 6 planes x 16384 ushort = 196608 B
    float* wsXU  = (float*)(ws + 196608);                       // 3 x 2048 x 128 fp32
    float* wsXX  = (float*)(ws + 3342336);                      // 2048 fp32

    hipLaunchKernelGGL(prep_w, dim3(3, 8), dim3(256), 0, stream, Wz, Wr, Wh, wsWT);
    hipLaunchKernelGGL(prep_xu, dim3(2048), dim3(256), 0, stream, x, Uz, Ur, Uh, wsXU, wsXX);
    hipLaunchKernelGGL(gru_fused, dim3(B_), dim3(512), 0, stream,
                       Wz, Wr, Wh, wsWT, wsXU, wsXX,
                       uzs, wzs, urs, wrs, uhs, whs, mu_out, S_out);
}

// Round 8
// 2405.275 us; speedup vs baseline: 1.0334x; 1.0334x over previous
//
#include <hip/hip_runtime.h>
#include <math.h>

#define B_ 64
#define T_ 32
#define D_ 128
#define N_ 128
#define ST 136      // ushort stride of staging-region rows (128 cols + 8 pad), 272 B
#define SS 132      // float stride of sS rows (128 cols + 4 pad), 528 B -> 4-bank rotation/row

typedef __attribute__((ext_vector_type(8))) short s8v;
typedef __attribute__((ext_vector_type(4))) float f4;

__device__ __forceinline__ float softplus_f(float v){ return (v > 20.f) ? v : log1pf(expf(v)); }
__device__ __forceinline__ float sigmoid_f(float v){ return 1.f / (1.f + expf(-v)); }
__device__ __forceinline__ float wred(float v){
#pragma unroll
    for (int o = 32; o > 0; o >>= 1) v += __shfl_down(v, o, 64);
    return v;
}
// fp32 -> bf16 hi (RN) + bf16 lo (RN of remainder): covers ~16 mantissa bits.
__device__ __forceinline__ void split2(float v, unsigned short& h, unsigned short& l){
    unsigned int u  = __float_as_uint(v);
    unsigned int rh = u + 0x7fffu + ((u >> 16) & 1u);
    h = (unsigned short)(rh >> 16);
    float fh = __uint_as_float(rh & 0xffff0000u);
    float lo = v - fh;
    unsigned int ul = __float_as_uint(lo);
    unsigned int rl = ul + 0x7fffu + ((ul >> 16) & 1u);
    l = (unsigned short)(rl >> 16);
}
__device__ __forceinline__ void split4_store(float4 v, unsigned short* hp, unsigned short* lp){
    unsigned short h0,h1,h2,h3,l0,l1,l2,l3;
    split2(v.x,h0,l0); split2(v.y,h1,l1); split2(v.z,h2,l2); split2(v.w,h3,l3);
    uint2 H = make_uint2((unsigned)h0 | ((unsigned)h1 << 16), (unsigned)h2 | ((unsigned)h3 << 16));
    uint2 L = make_uint2((unsigned)l0 | ((unsigned)l1 << 16), (unsigned)l2 | ((unsigned)l3 << 16));
    *(uint2*)hp = H; *(uint2*)lp = L;
}
__device__ __forceinline__ f4 mfma3(s8v ah, s8v al, s8v bh, s8v bl, f4 c){
    c = __builtin_amdgcn_mfma_f32_16x16x32_bf16(ah, bh, c, 0, 0, 0);
    c = __builtin_amdgcn_mfma_f32_16x16x32_bf16(ah, bl, c, 0, 0, 0);
    c = __builtin_amdgcn_mfma_f32_16x16x32_bf16(al, bh, c, 0, 0, 0);
    return c;
}

// ---- prep: split+transpose W into WT[n][l] bf16 hi/lo (n-major, l contiguous) ----
__global__ __launch_bounds__(256)
void prep_w(const float* __restrict__ Wz, const float* __restrict__ Wr,
            const float* __restrict__ Wh, unsigned short* __restrict__ WT){
    int gate = blockIdx.x, n0 = blockIdx.y * 16, tid = threadIdx.x;
    const float* W = (gate == 0) ? Wz : (gate == 1) ? Wr : Wh;
    unsigned short* hi = WT + (size_t)gate * 32768;
    unsigned short* lo = hi + 16384;
#pragma unroll
    for (int e = 0; e < 8; ++e){
        int idx = tid + e * 256;
        int n = n0 + (idx >> 7), k = idx & 127;
        float v = W[(size_t)k * 128 + n];
        unsigned short h, l; split2(v, h, l);
        hi[(size_t)n * 128 + k] = h;
        lo[(size_t)n * 128 + k] = l;
    }
}

// ---- prep: XU[g][bt][n] = x_bt . U_g  (g: 0=z,1=r,2=h), XX[bt] = ||x_bt||^2 ----
__global__ __launch_bounds__(256)
void prep_xu(const float* __restrict__ x, const float* __restrict__ Uz,
             const float* __restrict__ Ur, const float* __restrict__ Uh,
             float* __restrict__ XU, float* __restrict__ XX){
    int bt = blockIdx.x, tid = threadIdx.x;
    __shared__ float sX[128];
    __shared__ float sRed[256];
    __shared__ float sP[4];
    if (tid < 128) sX[tid] = x[(size_t)bt * 128 + tid];
    __syncthreads();
    {
        float v = (tid < 128) ? sX[tid] * sX[tid] : 0.f;
        v = wred(v);
        if ((tid & 63) == 0) sP[tid >> 6] = v;
    }
    const float* Us[3] = {Uz, Ur, Uh};
#pragma unroll 1
    for (int g = 0; g < 3; ++g){
        int n = tid & 127, hf = tid >> 7;
        float p = 0.f;
#pragma unroll 8
        for (int k = hf * 64; k < hf * 64 + 64; ++k) p = fmaf(sX[k], Us[g][(size_t)k * 128 + n], p);
        sRed[tid] = p;
        __syncthreads();
        if (tid < 128) XU[(size_t)g * (2048 * 128) + (size_t)bt * 128 + tid] = sRed[tid] + sRed[tid + 128];
        __syncthreads();
    }
    if (tid == 0) XX[bt] = sP[0] + sP[1] + sP[2] + sP[3];
}

// ---- fused recurrent kernel: one block per batch, full T loop in LDS ----
// Base = round-4 kernel (ran at 2283 us). ONE change: the z-epilogue is deferred
// to the final phase -- mm2-z's raw f4 accumulator (acc-class regs) stays live
// instead of a 32-float arch-VGPR array szc[32], whose 7-phase live range
// spilled ~125 MB/dispatch to scratch (measured: WRITE_SIZE 258 MB vs 132 MB
// true output in rounds 4 and 5).
__global__ __launch_bounds__(512, 2)
void gru_fused(const float* __restrict__ Wz, const float* __restrict__ Wr,
               const float* __restrict__ Wh,
               const unsigned short* __restrict__ WT,
               const float* __restrict__ XU, const float* __restrict__ XX,
               const float* __restrict__ uzs, const float* __restrict__ wzs,
               const float* __restrict__ urs, const float* __restrict__ wrs,
               const float* __restrict__ uhs, const float* __restrict__ whs,
               float* __restrict__ mu_out, float* __restrict__ S_out)
{
    const int b = blockIdx.x, tid = threadIdx.x;
    const int w8 = tid >> 6, wi = w8 & 3, wn = w8 >> 2;
    const int q = (tid >> 4) & 3, lm = tid & 15;

    __shared__ alignas(16) float sS[128 * SS];                  // fp32 state S_p (in-place updated)
    __shared__ alignas(16) unsigned short sRegion[2 * 128 * ST]; // hi plane @0, lo plane @128*ST
    __shared__ float sMuB[2][128];
    __shared__ float sZ[128], sGz[128], sR[128], sGr[128], sRh[128], sH[128], sGh[128];
    __shared__ float sSP[6][128];
    __shared__ float sRed[512];
    __shared__ float sScalTd[8];
    __shared__ float sScalP[2], sScalQ[2];
    __shared__ float sPt, sRR;

    unsigned short* sHi = sRegion;
    unsigned short* sLo = sRegion + 128 * ST;

    for (int i = tid; i < 128 * SS; i += 512) sS[i] = 0.f;
    for (int i = tid; i < 2 * 128 * ST; i += 512) sRegion[i] = 0;
    for (int a = tid; a < 768; a += 512){
        int tb = a >> 7, n = a & 127;
        const float* srcs[6] = {uzs, wzs, urs, wrs, uhs, whs};
        sSP[tb][n] = softplus_f(srcs[tb][n]);
    }
    if (tid < 128) sMuB[0][tid] = 0.f;
    __syncthreads();

    for (int t = 0; t < T_; ++t){
        const int bt = b * T_ + t;
        const float* muP = sMuB[t & 1];
        float* muN = sMuB[(t + 1) & 1];
        const float xxv = XX[bt];

        // prefetch gate biases: overlap L2 latency with P1/P3 FMA work
        float xuzr = 0.f, xuh = 0.f;
        if (tid < 256) xuzr = XU[(size_t)(tid >> 7) * (2048 * 128) + (size_t)bt * 128 + (tid & 127)];
        if (tid < 128) xuh = XU[(size_t)2 * (2048 * 128) + (size_t)bt * 128 + tid];

        // ---- P1: z/r matvec partials (split-K over 2) ----
        {
            int n = tid & 127, kq = (tid >> 7) & 1, g = tid >> 8;
            const float* Wg = g ? Wr : Wz;
            float p = 0.f;
#pragma unroll 8
            for (int k = kq * 64; k < kq * 64 + 64; ++k) p = fmaf(muP[k], Wg[(size_t)k * 128 + n], p);
            sRed[tid] = p;
        }
        __syncthreads();

        // ---- P2: finalize z, r, rh (threads 0-255); pp+trS reduce (256-383) ----
        if (tid < 256){
            int g = tid >> 7, n = tid & 127;
            float a = xuzr + sRed[g * 256 + n] + sRed[g * 256 + 128 + n];
            float gg = sigmoid_f(a);
            if (!g){ sZ[n] = gg; sGz[n] = gg * (1.f - gg); }
            else   { sR[n] = gg; sGr[n] = gg * (1.f - gg); sRh[n] = muP[n] * gg; }
        } else if (tid < 384){
            int n = tid & 127;
            float v = muP[n] * muP[n] + sS[n * (SS + 1)];
            v = wred(v);
            if ((tid & 63) == 0) sScalP[(tid >> 6) & 1] = v;
        }
        __syncthreads();

        // ---- P3: h matvec partials (split-K over 4) ----
        {
            int n = tid & 127, kq = tid >> 7;
            float p = 0.f;
#pragma unroll 8
            for (int k = kq * 32; k < kq * 32 + 32; ++k) p = fmaf(sRh[k], Wh[(size_t)k * 128 + n], p);
            sRed[tid] = p;
        }
        __syncthreads();

        // ---- P4: finalize h/mu (0-127); rr reduce (128-255); sPt (256) + mm1 ----
        if (tid < 128){
            float ah = xuh + sRed[tid] + sRed[tid + 128] + sRed[tid + 256] + sRed[tid + 384];
            float h = tanhf(ah);
            float z = sZ[tid];
            sH[tid] = h; sGh[tid] = 1.f - h * h;
            float m = z * muP[tid] + (1.f - z) * h;
            muN[tid] = m;
            __builtin_nontemporal_store(m, &mu_out[(size_t)bt * 128 + tid]);
        } else if (tid < 256){
            int n = tid & 127;
            float v = sRh[n] * sRh[n];
            v = wred(v);
            if ((tid & 63) == 0) sScalQ[(tid >> 6) & 1] = v;
        } else if (tid == 256){ sPt = sScalP[0] + sScalP[1]; }

        // ---- mm1: P_g = S_p . W_g for g=z,r (A = region S-split, B = WT) ----
        f4 accP[16];
#pragma unroll
        for (int i = 0; i < 16; ++i) accP[i] = (f4){0.f, 0.f, 0.f, 0.f};
#pragma unroll
        for (int c = 0; c < 4; ++c){
            int k0 = c * 32 + q * 8;
            s8v aH[2], aL[2];
#pragma unroll
            for (int s = 0; s < 2; ++s){
                int row = (wi * 2 + s) * 16 + lm;
                aH[s] = *(const s8v*)&sHi[row * ST + k0];
                aL[s] = *(const s8v*)&sLo[row * ST + k0];
            }
#pragma unroll
            for (int nt = 0; nt < 4; ++nt){
                size_t off = (size_t)(wn * 64 + nt * 16 + lm) * 128 + k0;
                s8v bzH = *(const s8v*)&WT[off];
                s8v bzL = *(const s8v*)&WT[16384 + off];
                s8v brH = *(const s8v*)&WT[32768 + off];
                s8v brL = *(const s8v*)&WT[49152 + off];
#pragma unroll
                for (int s = 0; s < 2; ++s){
                    accP[s * 4 + nt]     = mfma3(aH[s], aL[s], bzH, bzL, accP[s * 4 + nt]);
                    accP[8 + s * 4 + nt] = mfma3(aH[s], aL[s], brH, brL, accP[8 + s * 4 + nt]);
                }
            }
        }
        __syncthreads();    // mm1 done -> region free for PT_z

        // ---- PT_z stage: PT[n][i] = P_z[i][n] ----
#pragma unroll
        for (int s = 0; s < 2; ++s)
#pragma unroll
        for (int nt = 0; nt < 4; ++nt){
            f4 a = accP[s * 4 + nt];
            int kb = wi * 32 + s * 16 + q * 4;
            int jr = wn * 64 + nt * 16 + lm;
            split4_store(make_float4(a[0], a[1], a[2], a[3]),
                         &sHi[jr * ST + kb], &sLo[jr * ST + kb]);
        }
        if (tid == 0) sRR = sScalQ[0] + sScalQ[1];
        __syncthreads();

        // ---- mm2-z ONLY (epilogue-z deferred to final phase; raw acc kept) ----
        f4 accZ2[8];
#pragma unroll
        for (int i = 0; i < 8; ++i) accZ2[i] = (f4){0.f, 0.f, 0.f, 0.f};
#pragma unroll
        for (int c = 0; c < 4; ++c){
            int k0 = c * 32 + q * 8;
            s8v aH[2], aL[2];
#pragma unroll
            for (int s = 0; s < 2; ++s){
                size_t row = (size_t)((wi * 2 + s) * 16 + lm) * 128 + k0;
                aH[s] = *(const s8v*)&WT[row];
                aL[s] = *(const s8v*)&WT[16384 + row];
            }
#pragma unroll
            for (int nt = 0; nt < 4; ++nt){
                int j = wn * 64 + nt * 16 + lm;
                s8v bH = *(const s8v*)&sHi[j * ST + k0];
                s8v bL = *(const s8v*)&sLo[j * ST + k0];
#pragma unroll
                for (int s = 0; s < 2; ++s)
                    accZ2[s * 4 + nt] = mfma3(aH[s], aL[s], bH, bL, accZ2[s * 4 + nt]);
            }
        }
        __syncthreads();    // PT_z reads done -> region free for PT_r

        // ---- PT_r stage ----
#pragma unroll
        for (int s = 0; s < 2; ++s)
#pragma unroll
        for (int nt = 0; nt < 4; ++nt){
            f4 a = accP[8 + s * 4 + nt];
            int kb = wi * 32 + s * 16 + q * 4;
            int jr = wn * 64 + nt * 16 + lm;
            split4_store(make_float4(a[0], a[1], a[2], a[3]),
                         &sHi[jr * ST + kb], &sLo[jr * ST + kb]);
        }
        __syncthreads();

        // ---- mm2-r (MFMA only; epilogue after barrier since it overwrites region) ----
        f4 accR[8];
#pragma unroll
        for (int i = 0; i < 8; ++i) accR[i] = (f4){0.f, 0.f, 0.f, 0.f};
#pragma unroll
        for (int c = 0; c < 4; ++c){
            int k0 = c * 32 + q * 8;
            s8v aH[2], aL[2];
#pragma unroll
            for (int s = 0; s < 2; ++s){
                size_t row = (size_t)((wi * 2 + s) * 16 + lm) * 128 + k0;
                aH[s] = *(const s8v*)&WT[32768 + row];
                aL[s] = *(const s8v*)&WT[49152 + row];
            }
#pragma unroll
            for (int nt = 0; nt < 4; ++nt){
                int j = wn * 64 + nt * 16 + lm;
                s8v bH = *(const s8v*)&sHi[j * ST + k0];
                s8v bL = *(const s8v*)&sLo[j * ST + k0];
#pragma unroll
                for (int s = 0; s < 2; ++s)
                    accR[s * 4 + nt] = mfma3(aH[s], aL[s], bH, bL, accR[s * 4 + nt]);
            }
        }
        __syncthreads();    // PT_r reads done -> region free for S_g

        // ---- epilogue-r: Sr (regs only) -> S_g staged into region (transposed; S_g symmetric) ----
        {
            float pt = sPt;
            float td = 0.f;
#pragma unroll
            for (int s = 0; s < 2; ++s)
#pragma unroll
            for (int nt = 0; nt < 4; ++nt){
                f4 a = accR[s * 4 + nt];
                int ib = wi * 32 + s * 16 + q * 4;
                int j  = wn * 64 + nt * 16 + lm;
                float gj = sGr[j], muj = muP[j], rj = sR[j];
                float sg[4];
#pragma unroll
                for (int r = 0; r < 4; ++r){
                    int i = ib + r;
                    float v = a[r];
                    if (i == j) v += pt * sSP[3][i] + xxv * sSP[2][i];
                    float srv = v * sGr[i] * gj;                 // S_r[i][j]
                    float spv = sS[i * SS + j];
                    float gv = spv * srv + muP[i] * muj * srv + sR[i] * rj * spv;
                    if (i == j) td += gv;
                    sg[r] = gv;
                }
                // S_g symmetric: store S_g[i][j] at [j][i..i+3] (contiguous store)
                split4_store(make_float4(sg[0], sg[1], sg[2], sg[3]),
                             &sHi[j * ST + ib], &sLo[j * ST + ib]);
            }
            td = wred(td);
            if ((tid & 63) == 0) sScalTd[w8] = td;
        }
        __syncthreads();

        // ---- mm1-h: P_h = S_g . W_h ----
        f4 accH[8];
#pragma unroll
        for (int i = 0; i < 8; ++i) accH[i] = (f4){0.f, 0.f, 0.f, 0.f};
#pragma unroll
        for (int c = 0; c < 4; ++c){
            int k0 = c * 32 + q * 8;
            s8v aH[2], aL[2];
#pragma unroll
            for (int s = 0; s < 2; ++s){
                int row = (wi * 2 + s) * 16 + lm;
                aH[s] = *(const s8v*)&sHi[row * ST + k0];
                aL[s] = *(const s8v*)&sLo[row * ST + k0];
            }
#pragma unroll
            for (int nt = 0; nt < 4; ++nt){
                size_t off = (size_t)(wn * 64 + nt * 16 + lm) * 128 + k0;
                s8v bH = *(const s8v*)&WT[65536 + off];
                s8v bL = *(const s8v*)&WT[81920 + off];
#pragma unroll
                for (int s = 0; s < 2; ++s)
                    accH[s * 4 + nt] = mfma3(aH[s], aL[s], bH, bL, accH[s * 4 + nt]);
            }
        }
        __syncthreads();    // mm1-h done -> region free for PT_h

        // ---- PT_h stage ----
#pragma unroll
        for (int s = 0; s < 2; ++s)
#pragma unroll
        for (int nt = 0; nt < 4; ++nt){
            f4 a = accH[s * 4 + nt];
            int kb = wi * 32 + s * 16 + q * 4;
            int jr = wn * 64 + nt * 16 + lm;
            split4_store(make_float4(a[0], a[1], a[2], a[3]),
                         &sHi[jr * ST + kb], &sLo[jr * ST + kb]);
        }
        __syncthreads();

        // ---- mm2-h ----
        f4 accC[8];
#pragma unroll
        for (int i = 0; i < 8; ++i) accC[i] = (f4){0.f, 0.f, 0.f, 0.f};
#pragma unroll
        for (int c = 0; c < 4; ++c){
            int k0 = c * 32 + q * 8;
            s8v aH[2], aL[2];
#pragma unroll
            for (int s = 0; s < 2; ++s){
                size_t row = (size_t)((wi * 2 + s) * 16 + lm) * 128 + k0;
                aH[s] = *(const s8v*)&WT[65536 + row];
                aL[s] = *(const s8v*)&WT[81920 + row];
            }
#pragma unroll
            for (int nt = 0; nt < 4; ++nt){
                int j = wn * 64 + nt * 16 + lm;
                s8v bH = *(const s8v*)&sHi[j * ST + k0];
                s8v bL = *(const s8v*)&sLo[j * ST + k0];
#pragma unroll
                for (int s = 0; s < 2; ++s)
                    accC[s * 4 + nt] = mfma3(aH[s], aL[s], bH, bL, accC[s * 4 + nt]);
            }
        }
        __syncthreads();    // PT_h reads done -> region free for next S-split

        // ---- final epilogue: z-epilogue (deferred) + S_h + combine; update sS;
        //      NT-write S_out; stage next S-split ----
        {
            float trg = 0.f;
#pragma unroll
            for (int k = 0; k < 8; ++k) trg += sScalTd[k];
            float coef = sRR + trg;                 // rr + tr(S_g)
            float ptv  = sPt;                       // pp + trS
            float* outS = S_out + (size_t)bt * 16384;
#pragma unroll
            for (int s = 0; s < 2; ++s)
#pragma unroll
            for (int nt = 0; nt < 4; ++nt){
                f4 a  = accC[s * 4 + nt];
                f4 az = accZ2[s * 4 + nt];
                int ib = wi * 32 + s * 16 + q * 4;
                int j  = wn * 64 + nt * 16 + lm;
                float zj = sZ[j], ghj = sGh[j], gzj = sGz[j], dmj = muP[j] - sH[j];
                f4 sv4;
#pragma unroll
                for (int r = 0; r < 4; ++r){
                    int i = ib + r;
                    float vz = az[r];
                    if (i == j) vz += ptv * sSP[1][i] + xxv * sSP[0][i];
                    float szv = vz * sGz[i] * gzj;               // S_z[i][j]
                    float shh = a[r];
                    if (i == j) shh += coef * sSP[5][i] + xxv * sSP[4][i];
                    float sh = shh * sGh[i] * ghj;               // S_h[i][j]
                    float spv = sS[i * SS + j];
                    float dmi = muP[i] - sH[i];
                    float zi = sZ[i];
                    float sv = szv * (spv + sh + dmi * dmj) + zi * zj * spv + (1.f - zi) * (1.f - zj) * sh;
                    if (!isfinite(sv)) sv = 0.f;
                    if (i == j) sv = fabsf(sv);
                    sS[i * SS + j] = sv;            // owner-matched in-place update (no race)
                    sv4[r] = sv;
                }
                // S symmetric: thread's 4 values are S[j][ib..ib+3] -> one NT float4 row store
                __builtin_nontemporal_store(sv4, (f4*)&outS[(size_t)j * 128 + ib]);
                // next-step S-split staged transposed (S symmetric up to split eps)
                split4_store(make_float4(sv4[0], sv4[1], sv4[2], sv4[3]),
                             &sHi[j * ST + ib], &sLo[j * ST + ib]);
            }
        }
        __syncthreads();    // end of step: sS / region / muN visible
    }
}

extern "C" void kernel_launch(void* const* d_in, const int* in_sizes, int n_in,
                              void* d_out, int out_size, void* d_ws, size_t ws_size,
                              hipStream_t stream)
{
    (void)in_sizes; (void)n_in; (void)out_size; (void)ws_size;
    const float* x   = (const float*)d_in[0];
    const float* Uz  = (const float*)d_in[1];
    const float* Wz  = (const float*)d_in[2];
    const float* Ur  = (const float*)d_in[3];
    const float* Wr  = (const float*)d_in[4];
    const float* Uh  = (const float*)d_in[5];
    const float* Wh  = (const float*)d_in[6];
    const float* uzs = (const float*)d_in[7];
    const float* wzs = (const float*)d_in[8];
    const float* urs = (const float*)d_in[9];
    const float* wrs = (const float*)d_in[10];
    const float* uhs = (const float*)d_in[11];
    const float* whs = (const float*)d_in[12];

    float* mu_out = (float*)d_out;
    float* S_out  = (float*)d_out + (size_t)B_ * T_ * N_;

    char* ws = (char*)d_ws;
    unsigned short* wsWT = (unsigned short*)ws;                 // 6 planes x 16384 ushort = 196608 B
    float* wsXU  = (float*)(ws + 196608);                       // 3 x 2048 x 128 fp32
    float* wsXX  = (float*)(ws + 3342336);                      // 2048 fp32

    hipLaunchKernelGGL(prep_w, dim3(3, 8), dim3(256), 0, stream, Wz, Wr, Wh, wsWT);
    hipLaunchKernelGGL(prep_xu, dim3(2048), dim3(256), 0, stream, x, Uz, Ur, Uh, wsXU, wsXX);
    hipLaunchKernelGGL(gru_fused, dim3(B_), dim3(512), 0, stream,
                       Wz, Wr, Wh, wsWT, wsXU, wsXX,
                       uzs, wzs, urs, wrs, uhs, whs, mu_out, S_out);
}

// Round 9
// 1990.983 us; speedup vs baseline: 1.2484x; 1.2081x over previous
//
#include <hip/hip_runtime.h>
#include <math.h>

#define B_ 64
#define T_ 32
#define D_ 128
#define N_ 128
#define ST 136      // ushort stride of staging-region rows (128 cols + 8 pad), 272 B
#define SS 132      // float stride of sS rows (128 cols + 4 pad), 528 B -> 4-bank rotation/row

typedef __attribute__((ext_vector_type(8))) short s8v;
typedef __attribute__((ext_vector_type(4))) float f4;

__device__ __forceinline__ float softplus_f(float v){ return (v > 20.f) ? v : log1pf(expf(v)); }
__device__ __forceinline__ float sigmoid_f(float v){ return 1.f / (1.f + expf(-v)); }
__device__ __forceinline__ float wred(float v){
#pragma unroll
    for (int o = 32; o > 0; o >>= 1) v += __shfl_down(v, o, 64);
    return v;
}
// fp32 -> bf16 hi (RN) + bf16 lo (RN of remainder): covers ~16 mantissa bits.
__device__ __forceinline__ void split2(float v, unsigned short& h, unsigned short& l){
    unsigned int u  = __float_as_uint(v);
    unsigned int rh = u + 0x7fffu + ((u >> 16) & 1u);
    h = (unsigned short)(rh >> 16);
    float fh = __uint_as_float(rh & 0xffff0000u);
    float lo = v - fh;
    unsigned int ul = __float_as_uint(lo);
    unsigned int rl = ul + 0x7fffu + ((ul >> 16) & 1u);
    l = (unsigned short)(rl >> 16);
}
__device__ __forceinline__ void split4_store(float4 v, unsigned short* hp, unsigned short* lp){
    unsigned short h0,h1,h2,h3,l0,l1,l2,l3;
    split2(v.x,h0,l0); split2(v.y,h1,l1); split2(v.z,h2,l2); split2(v.w,h3,l3);
    uint2 H = make_uint2((unsigned)h0 | ((unsigned)h1 << 16), (unsigned)h2 | ((unsigned)h3 << 16));
    uint2 L = make_uint2((unsigned)l0 | ((unsigned)l1 << 16), (unsigned)l2 | ((unsigned)l3 << 16));
    *(uint2*)hp = H; *(uint2*)lp = L;
}
__device__ __forceinline__ f4 mfma3(s8v ah, s8v al, s8v bh, s8v bl, f4 c){
    c = __builtin_amdgcn_mfma_f32_16x16x32_bf16(ah, bh, c, 0, 0, 0);
    c = __builtin_amdgcn_mfma_f32_16x16x32_bf16(ah, bl, c, 0, 0, 0);
    c = __builtin_amdgcn_mfma_f32_16x16x32_bf16(al, bh, c, 0, 0, 0);
    return c;
}

// ---- prep: split+transpose W into WT[n][l] bf16 hi/lo (n-major, l contiguous) ----
__global__ __launch_bounds__(256)
void prep_w(const float* __restrict__ Wz, const float* __restrict__ Wr,
            const float* __restrict__ Wh, unsigned short* __restrict__ WT){
    int gate = blockIdx.x, n0 = blockIdx.y * 16, tid = threadIdx.x;
    const float* W = (gate == 0) ? Wz : (gate == 1) ? Wr : Wh;
    unsigned short* hi = WT + (size_t)gate * 32768;
    unsigned short* lo = hi + 16384;
#pragma unroll
    for (int e = 0; e < 8; ++e){
        int idx = tid + e * 256;
        int n = n0 + (idx >> 7), k = idx & 127;
        float v = W[(size_t)k * 128 + n];
        unsigned short h, l; split2(v, h, l);
        hi[(size_t)n * 128 + k] = h;
        lo[(size_t)n * 128 + k] = l;
    }
}

// ---- prep: XU[g][bt][n] = x_bt . U_g  (g: 0=z,1=r,2=h), XX[bt] = ||x_bt||^2 ----
__global__ __launch_bounds__(256)
void prep_xu(const float* __restrict__ x, const float* __restrict__ Uz,
             const float* __restrict__ Ur, const float* __restrict__ Uh,
             float* __restrict__ XU, float* __restrict__ XX){
    int bt = blockIdx.x, tid = threadIdx.x;
    __shared__ float sX[128];
    __shared__ float sRed[256];
    __shared__ float sP[4];
    if (tid < 128) sX[tid] = x[(size_t)bt * 128 + tid];
    __syncthreads();
    {
        float v = (tid < 128) ? sX[tid] * sX[tid] : 0.f;
        v = wred(v);
        if ((tid & 63) == 0) sP[tid >> 6] = v;
    }
    const float* Us[3] = {Uz, Ur, Uh};
#pragma unroll 1
    for (int g = 0; g < 3; ++g){
        int n = tid & 127, hf = tid >> 7;
        float p = 0.f;
#pragma unroll 8
        for (int k = hf * 64; k < hf * 64 + 64; ++k) p = fmaf(sX[k], Us[g][(size_t)k * 128 + n], p);
        sRed[tid] = p;
        __syncthreads();
        if (tid < 128) XU[(size_t)g * (2048 * 128) + (size_t)bt * 128 + tid] = sRed[tid] + sRed[tid + 128];
        __syncthreads();
    }
    if (tid == 0) XX[bt] = sP[0] + sP[1] + sP[2] + sP[3];
}

// ---- fused recurrent kernel: one block per batch, full T loop in LDS ----
// Base = round-8 (proven). Changes this round:
// (1) S_out written COALESCED (full 64B lines, NT) from fp32 sS in the next
//     step's P1 phase -- the old per-cell store was 16B @ 512B stride, which
//     2x-amplified writes (WRITE_SIZE 258 vs 129 MB true) and churned L2,
//     evicting weights every step (FETCH 1.14 GB = all weights re-fetched/step).
// (2) P1/P3 gate matvecs use float4 W loads: 96 -> 24 load instrs/thread
//     (same bytes) -- fewer latency exposures in the latency-bound regime.
__global__ __launch_bounds__(512, 2)
void gru_fused(const float* __restrict__ Wz, const float* __restrict__ Wr,
               const float* __restrict__ Wh,
               const unsigned short* __restrict__ WT,
               const float* __restrict__ XU, const float* __restrict__ XX,
               const float* __restrict__ uzs, const float* __restrict__ wzs,
               const float* __restrict__ urs, const float* __restrict__ wrs,
               const float* __restrict__ uhs, const float* __restrict__ whs,
               float* __restrict__ mu_out, float* __restrict__ S_out)
{
    const int b = blockIdx.x, tid = threadIdx.x;
    const int w8 = tid >> 6, wi = w8 & 3, wn = w8 >> 2;
    const int q = (tid >> 4) & 3, lm = tid & 15;

    __shared__ alignas(16) float sS[128 * SS];                  // fp32 state S_p (in-place updated)
    __shared__ alignas(16) unsigned short sRegion[2 * 128 * ST]; // hi plane @0, lo plane @128*ST
    __shared__ alignas(16) f4 sRed4[512];
    __shared__ float sMuB[2][128];
    __shared__ float sZ[128], sGz[128], sR[128], sGr[128], sRh[128], sH[128], sGh[128];
    __shared__ float sSP[6][128];
    __shared__ float sScalTd[8];
    __shared__ float sScalP[2], sScalQ[2];
    __shared__ float sPt, sRR;

    unsigned short* sHi = sRegion;
    unsigned short* sLo = sRegion + 128 * ST;

    for (int i = tid; i < 128 * SS; i += 512) sS[i] = 0.f;
    for (int i = tid; i < 2 * 128 * ST; i += 512) sRegion[i] = 0;
    for (int a = tid; a < 768; a += 512){
        int tb = a >> 7, n = a & 127;
        const float* srcs[6] = {uzs, wzs, urs, wrs, uhs, whs};
        sSP[tb][n] = softplus_f(srcs[tb][n]);
    }
    if (tid < 128) sMuB[0][tid] = 0.f;
    __syncthreads();

    for (int t = 0; t < T_; ++t){
        const int bt = b * T_ + t;
        const float* muP = sMuB[t & 1];
        float* muN = sMuB[(t + 1) & 1];
        const float xxv = XX[bt];

        // prefetch gate biases: overlap L2 latency with P1/P3 FMA work
        float xuzr = 0.f, xuh = 0.f;
        if (tid < 256) xuzr = XU[(size_t)(tid >> 7) * (2048 * 128) + (size_t)bt * 128 + (tid & 127)];
        if (tid < 128) xuh = XU[(size_t)2 * (2048 * 128) + (size_t)bt * 128 + tid];

        // ---- P1: z/r matvec partials (float4 W loads) + coalesced S_out(t-1) write ----
        {
            int g = tid >> 8, t8 = tid & 255;
            int ng = t8 & 31, kq = t8 >> 5;                 // 8 k-chunks of 16
            const float* Wg = g ? Wr : Wz;
            const float* Wp = Wg + (size_t)(kq * 16) * 128 + ng * 4;
            f4 p = {0.f, 0.f, 0.f, 0.f};
#pragma unroll
            for (int k = 0; k < 16; ++k){
                f4 w = *(const f4*)(Wp + (size_t)k * 128);
                float m = muP[kq * 16 + k];
                p[0] = fmaf(m, w[0], p[0]); p[1] = fmaf(m, w[1], p[1]);
                p[2] = fmaf(m, w[2], p[2]); p[3] = fmaf(m, w[3], p[3]);
            }
            sRed4[tid] = p;                                  // idx = g*256 + kq*32 + ng
        }
        if (t > 0){
            // write S_out for step t-1 from sS: 4 lanes x 16B = 64B full lines, NT
            float* outP = S_out + (size_t)(bt - 1) * 16384;
            int row = tid >> 2, cb = (tid & 3) * 4;
#pragma unroll
            for (int u = 0; u < 8; ++u){
                int col = cb + u * 16;
                f4 v = *(const f4*)&sS[row * SS + col];
                __builtin_nontemporal_store(v, (f4*)&outP[row * 128 + col]);
            }
        }
        __syncthreads();

        // ---- P2: finalize z, r, rh (threads 0-255); pp+trS reduce (256-383) ----
        if (tid < 256){
            int g = tid >> 7, n = tid & 127;
            const float* base = (const float*)(sRed4 + g * 256 + (n >> 2));
            float a = xuzr;
#pragma unroll
            for (int kq = 0; kq < 8; ++kq) a += base[kq * 128 + (n & 3)];
            float gg = sigmoid_f(a);
            if (!g){ sZ[n] = gg; sGz[n] = gg * (1.f - gg); }
            else   { sR[n] = gg; sGr[n] = gg * (1.f - gg); sRh[n] = muP[n] * gg; }
        } else if (tid < 384){
            int n = tid & 127;
            float v = muP[n] * muP[n] + sS[n * (SS + 1)];
            v = wred(v);
            if ((tid & 63) == 0) sScalP[(tid >> 6) & 1] = v;
        }
        __syncthreads();

        // ---- P3: h matvec partials (float4 W loads) ----
        {
            int ng = tid & 31, kq = tid >> 5;                // 16 k-chunks of 8
            const float* Wp = Wh + (size_t)(kq * 8) * 128 + ng * 4;
            f4 p = {0.f, 0.f, 0.f, 0.f};
#pragma unroll
            for (int k = 0; k < 8; ++k){
                f4 w = *(const f4*)(Wp + (size_t)k * 128);
                float m = sRh[kq * 8 + k];
                p[0] = fmaf(m, w[0], p[0]); p[1] = fmaf(m, w[1], p[1]);
                p[2] = fmaf(m, w[2], p[2]); p[3] = fmaf(m, w[3], p[3]);
            }
            sRed4[tid] = p;                                  // idx = kq*32 + ng
        }
        __syncthreads();

        // ---- P4: finalize h/mu (0-127); rr reduce (128-255); sPt (256) + mm1 ----
        if (tid < 128){
            int n = tid;
            const float* base = (const float*)(sRed4 + (n >> 2));
            float ah = xuh;
#pragma unroll
            for (int kq = 0; kq < 16; ++kq) ah += base[kq * 128 + (n & 3)];
            float h = tanhf(ah);
            float z = sZ[n];
            sH[n] = h; sGh[n] = 1.f - h * h;
            float m = z * muP[n] + (1.f - z) * h;
            muN[n] = m;
            __builtin_nontemporal_store(m, &mu_out[(size_t)bt * 128 + n]);
        } else if (tid < 256){
            int n = tid & 127;
            float v = sRh[n] * sRh[n];
            v = wred(v);
            if ((tid & 63) == 0) sScalQ[(tid >> 6) & 1] = v;
        } else if (tid == 256){ sPt = sScalP[0] + sScalP[1]; }

        // ---- mm1: P_g = S_p . W_g for g=z,r (A = region S-split, B = WT) ----
        f4 accP[16];
#pragma unroll
        for (int i = 0; i < 16; ++i) accP[i] = (f4){0.f, 0.f, 0.f, 0.f};
#pragma unroll
        for (int c = 0; c < 4; ++c){
            int k0 = c * 32 + q * 8;
            s8v aH[2], aL[2];
#pragma unroll
            for (int s = 0; s < 2; ++s){
                int row = (wi * 2 + s) * 16 + lm;
                aH[s] = *(const s8v*)&sHi[row * ST + k0];
                aL[s] = *(const s8v*)&sLo[row * ST + k0];
            }
#pragma unroll
            for (int nt = 0; nt < 4; ++nt){
                size_t off = (size_t)(wn * 64 + nt * 16 + lm) * 128 + k0;
                s8v bzH = *(const s8v*)&WT[off];
                s8v bzL = *(const s8v*)&WT[16384 + off];
                s8v brH = *(const s8v*)&WT[32768 + off];
                s8v brL = *(const s8v*)&WT[49152 + off];
#pragma unroll
                for (int s = 0; s < 2; ++s){
                    accP[s * 4 + nt]     = mfma3(aH[s], aL[s], bzH, bzL, accP[s * 4 + nt]);
                    accP[8 + s * 4 + nt] = mfma3(aH[s], aL[s], brH, brL, accP[8 + s * 4 + nt]);
                }
            }
        }
        __syncthreads();    // mm1 done -> region free for PT_z

        // ---- PT_z stage: PT[n][i] = P_z[i][n] ----
#pragma unroll
        for (int s = 0; s < 2; ++s)
#pragma unroll
        for (int nt = 0; nt < 4; ++nt){
            f4 a = accP[s * 4 + nt];
            int kb = wi * 32 + s * 16 + q * 4;
            int jr = wn * 64 + nt * 16 + lm;
            split4_store(make_float4(a[0], a[1], a[2], a[3]),
                         &sHi[jr * ST + kb], &sLo[jr * ST + kb]);
        }
        if (tid == 0) sRR = sScalQ[0] + sScalQ[1];
        __syncthreads();

        // ---- mm2-z ONLY (epilogue-z deferred to final phase; raw acc kept) ----
        f4 accZ2[8];
#pragma unroll
        for (int i = 0; i < 8; ++i) accZ2[i] = (f4){0.f, 0.f, 0.f, 0.f};
#pragma unroll
        for (int c = 0; c < 4; ++c){
            int k0 = c * 32 + q * 8;
            s8v aH[2], aL[2];
#pragma unroll
            for (int s = 0; s < 2; ++s){
                size_t row = (size_t)((wi * 2 + s) * 16 + lm) * 128 + k0;
                aH[s] = *(const s8v*)&WT[row];
                aL[s] = *(const s8v*)&WT[16384 + row];
            }
#pragma unroll
            for (int nt = 0; nt < 4; ++nt){
                int j = wn * 64 + nt * 16 + lm;
                s8v bH = *(const s8v*)&sHi[j * ST + k0];
                s8v bL = *(const s8v*)&sLo[j * ST + k0];
#pragma unroll
                for (int s = 0; s < 2; ++s)
                    accZ2[s * 4 + nt] = mfma3(aH[s], aL[s], bH, bL, accZ2[s * 4 + nt]);
            }
        }
        __syncthreads();    // PT_z reads done -> region free for PT_r

        // ---- PT_r stage ----
#pragma unroll
        for (int s = 0; s < 2; ++s)
#pragma unroll
        for (int nt = 0; nt < 4; ++nt){
            f4 a = accP[8 + s * 4 + nt];
            int kb = wi * 32 + s * 16 + q * 4;
            int jr = wn * 64 + nt * 16 + lm;
            split4_store(make_float4(a[0], a[1], a[2], a[3]),
                         &sHi[jr * ST + kb], &sLo[jr * ST + kb]);
        }
        __syncthreads();

        // ---- mm2-r (MFMA only; epilogue after barrier since it overwrites region) ----
        f4 accR[8];
#pragma unroll
        for (int i = 0; i < 8; ++i) accR[i] = (f4){0.f, 0.f, 0.f, 0.f};
#pragma unroll
        for (int c = 0; c < 4; ++c){
            int k0 = c * 32 + q * 8;
            s8v aH[2], aL[2];
#pragma unroll
            for (int s = 0; s < 2; ++s){
                size_t row = (size_t)((wi * 2 + s) * 16 + lm) * 128 + k0;
                aH[s] = *(const s8v*)&WT[32768 + row];
                aL[s] = *(const s8v*)&WT[49152 + row];
            }
#pragma unroll
            for (int nt = 0; nt < 4; ++nt){
                int j = wn * 64 + nt * 16 + lm;
                s8v bH = *(const s8v*)&sHi[j * ST + k0];
                s8v bL = *(const s8v*)&sLo[j * ST + k0];
#pragma unroll
                for (int s = 0; s < 2; ++s)
                    accR[s * 4 + nt] = mfma3(aH[s], aL[s], bH, bL, accR[s * 4 + nt]);
            }
        }
        __syncthreads();    // PT_r reads done -> region free for S_g

        // ---- epilogue-r: Sr (regs only) -> S_g staged into region (transposed; S_g symmetric) ----
        {
            float pt = sPt;
            float td = 0.f;
#pragma unroll
            for (int s = 0; s < 2; ++s)
#pragma unroll
            for (int nt = 0; nt < 4; ++nt){
                f4 a = accR[s * 4 + nt];
                int ib = wi * 32 + s * 16 + q * 4;
                int j  = wn * 64 + nt * 16 + lm;
                float gj = sGr[j], muj = muP[j], rj = sR[j];
                float sg[4];
#pragma unroll
                for (int r = 0; r < 4; ++r){
                    int i = ib + r;
                    float v = a[r];
                    if (i == j) v += pt * sSP[3][i] + xxv * sSP[2][i];
                    float srv = v * sGr[i] * gj;                 // S_r[i][j]
                    float spv = sS[i * SS + j];
                    float gv = spv * srv + muP[i] * muj * srv + sR[i] * rj * spv;
                    if (i == j) td += gv;
                    sg[r] = gv;
                }
                // S_g symmetric: store S_g[i][j] at [j][i..i+3] (contiguous store)
                split4_store(make_float4(sg[0], sg[1], sg[2], sg[3]),
                             &sHi[j * ST + ib], &sLo[j * ST + ib]);
            }
            td = wred(td);
            if ((tid & 63) == 0) sScalTd[w8] = td;
        }
        __syncthreads();

        // ---- mm1-h: P_h = S_g . W_h ----
        f4 accH[8];
#pragma unroll
        for (int i = 0; i < 8; ++i) accH[i] = (f4){0.f, 0.f, 0.f, 0.f};
#pragma unroll
        for (int c = 0; c < 4; ++c){
            int k0 = c * 32 + q * 8;
            s8v aH[2], aL[2];
#pragma unroll
            for (int s = 0; s < 2; ++s){
                int row = (wi * 2 + s) * 16 + lm;
                aH[s] = *(const s8v*)&sHi[row * ST + k0];
                aL[s] = *(const s8v*)&sLo[row * ST + k0];
            }
#pragma unroll
            for (int nt = 0; nt < 4; ++nt){
                size_t off = (size_t)(wn * 64 + nt * 16 + lm) * 128 + k0;
                s8v bH = *(const s8v*)&WT[65536 + off];
                s8v bL = *(const s8v*)&WT[81920 + off];
#pragma unroll
                for (int s = 0; s < 2; ++s)
                    accH[s * 4 + nt] = mfma3(aH[s], aL[s], bH, bL, accH[s * 4 + nt]);
            }
        }
        __syncthreads();    // mm1-h done -> region free for PT_h

        // ---- PT_h stage ----
#pragma unroll
        for (int s = 0; s < 2; ++s)
#pragma unroll
        for (int nt = 0; nt < 4; ++nt){
            f4 a = accH[s * 4 + nt];
            int kb = wi * 32 + s * 16 + q * 4;
            int jr = wn * 64 + nt * 16 + lm;
            split4_store(make_float4(a[0], a[1], a[2], a[3]),
                         &sHi[jr * ST + kb], &sLo[jr * ST + kb]);
        }
        __syncthreads();

        // ---- mm2-h ----
        f4 accC[8];
#pragma unroll
        for (int i = 0; i < 8; ++i) accC[i] = (f4){0.f, 0.f, 0.f, 0.f};
#pragma unroll
        for (int c = 0; c < 4; ++c){
            int k0 = c * 32 + q * 8;
            s8v aH[2], aL[2];
#pragma unroll
            for (int s = 0; s < 2; ++s){
                size_t row = (size_t)((wi * 2 + s) * 16 + lm) * 128 + k0;
                aH[s] = *(const s8v*)&WT[65536 + row];
                aL[s] = *(const s8v*)&WT[81920 + row];
            }
#pragma unroll
            for (int nt = 0; nt < 4; ++nt){
                int j = wn * 64 + nt * 16 + lm;
                s8v bH = *(const s8v*)&sHi[j * ST + k0];
                s8v bL = *(const s8v*)&sLo[j * ST + k0];
#pragma unroll
                for (int s = 0; s < 2; ++s)
                    accC[s * 4 + nt] = mfma3(aH[s], aL[s], bH, bL, accC[s * 4 + nt]);
            }
        }
        __syncthreads();    // PT_h reads done -> region free for next S-split

        // ---- final epilogue: z-epilogue (deferred) + S_h + combine; update sS;
        //      stage next S-split (S_out written coalesced next step) ----
        {
            float trg = 0.f;
#pragma unroll
            for (int k = 0; k < 8; ++k) trg += sScalTd[k];
            float coef = sRR + trg;                 // rr + tr(S_g)
            float ptv  = sPt;                       // pp + trS
#pragma unroll
            for (int s = 0; s < 2; ++s)
#pragma unroll
            for (int nt = 0; nt < 4; ++nt){
                f4 a  = accC[s * 4 + nt];
                f4 az = accZ2[s * 4 + nt];
                int ib = wi * 32 + s * 16 + q * 4;
                int j  = wn * 64 + nt * 16 + lm;
                float zj = sZ[j], ghj = sGh[j], gzj = sGz[j], dmj = muP[j] - sH[j];
                f4 sv4;
#pragma unroll
                for (int r = 0; r < 4; ++r){
                    int i = ib + r;
                    float vz = az[r];
                    if (i == j) vz += ptv * sSP[1][i] + xxv * sSP[0][i];
                    float szv = vz * sGz[i] * gzj;               // S_z[i][j]
                    float shh = a[r];
                    if (i == j) shh += coef * sSP[5][i] + xxv * sSP[4][i];
                    float sh = shh * sGh[i] * ghj;               // S_h[i][j]
                    float spv = sS[i * SS + j];
                    float dmi = muP[i] - sH[i];
                    float zi = sZ[i];
                    float sv = szv * (spv + sh + dmi * dmj) + zi * zj * spv + (1.f - zi) * (1.f - zj) * sh;
                    if (!isfinite(sv)) sv = 0.f;
                    if (i == j) sv = fabsf(sv);
                    sS[i * SS + j] = sv;            // owner-matched in-place update (no race)
                    sv4[r] = sv;
                }
                // next-step S-split staged transposed (S symmetric up to split eps)
                split4_store(make_float4(sv4[0], sv4[1], sv4[2], sv4[3]),
                             &sHi[j * ST + ib], &sLo[j * ST + ib]);
            }
        }
        __syncthreads();    // end of step: sS / region / muN visible
    }

    // ---- tail: write S_out for the final step (coalesced, NT) ----
    {
        float* outP = S_out + (size_t)(b * T_ + T_ - 1) * 16384;
        int row = tid >> 2, cb = (tid & 3) * 4;
#pragma unroll
        for (int u = 0; u < 8; ++u){
            int col = cb + u * 16;
            f4 v = *(const f4*)&sS[row * SS + col];
            __builtin_nontemporal_store(v, (f4*)&outP[row * 128 + col]);
        }
    }
}

extern "C" void kernel_launch(void* const* d_in, const int* in_sizes, int n_in,
                              void* d_out, int out_size, void* d_ws, size_t ws_size,
                              hipStream_t stream)
{
    (void)in_sizes; (void)n_in; (void)out_size; (void)ws_size;
    const float* x   = (const float*)d_in[0];
    const float* Uz  = (const float*)d_in[1];
    const float* Wz  = (const float*)d_in[2];
    const float* Ur  = (const float*)d_in[3];
    const float* Wr  = (const float*)d_in[4];
    const float* Uh  = (const float*)d_in[5];
    const float* Wh  = (const float*)d_in[6];
    const float* uzs = (const float*)d_in[7];
    const float* wzs = (const float*)d_in[8];
    const float* urs = (const float*)d_in[9];
    const float* wrs = (const float*)d_in[10];
    const float* uhs = (const float*)d_in[11];
    const float* whs = (const float*)d_in[12];

    float* mu_out = (float*)d_out;
    float* S_out  = (float*)d_out + (size_t)B_ * T_ * N_;

    char* ws = (char*)d_ws;
    unsigned short* wsWT = (unsigned short*)ws;                 // 6 planes x 16384 ushort = 196608 B
    float* wsXU  = (float*)(ws + 196608);                       // 3 x 2048 x 128 fp32
    float* wsXX  = (float*)(ws + 3342336);                      // 2048 fp32

    hipLaunchKernelGGL(prep_w, dim3(3, 8), dim3(256), 0, stream, Wz, Wr, Wh, wsWT);
    hipLaunchKernelGGL(prep_xu, dim3(2048), dim3(256), 0, stream, x, Uz, Ur, Uh, wsXU, wsXX);
    hipLaunchKernelGGL(gru_fused, dim3(B_), dim3(512), 0, stream,
                       Wz, Wr, Wh, wsWT, wsXU, wsXX,
                       uzs, wzs, urs, wrs, uhs, whs, mu_out, S_out);
}